// Round 3
// baseline (367.381 us; speedup 1.0000x reference)
//
#include <hip/hip_runtime.h>
#include <hip/hip_bf16.h>

#define DIM 512
#define BATCH 512
#define CCLS 100000
#define BM 256
#define BN 128
#define NT 782   // ceil(100000/128)

typedef __attribute__((ext_vector_type(8))) short bf16x8;
typedef __attribute__((ext_vector_type(4))) float f32x4;

__device__ __forceinline__ unsigned short f2bf(float f) {
  union { float f; unsigned int u; } v; v.f = f;
  unsigned int u = v.u;
  return (unsigned short)((u + 0x7fffu + ((u >> 16) & 1u)) >> 16);
}

__device__ __forceinline__ void async_copy16(const unsigned short* g, unsigned short* l) {
  __builtin_amdgcn_global_load_lds((const __attribute__((address_space(1))) void*)g,
                                   (__attribute__((address_space(3))) void*)l, 16, 0, 0);
}

// One wave per row: read fp32 row, L2-normalize, write bf16 row.
__global__ __launch_bounds__(256) void rownorm_all(const float* __restrict__ wt,
                                                   const float* __restrict__ x,
                                                   unsigned short* __restrict__ wn,
                                                   unsigned short* __restrict__ xn) {
  int wave = threadIdx.x >> 6;
  int lane = threadIdx.x & 63;
  int row4 = blockIdx.x * 4 + wave;
  const float* in;
  unsigned short* out;
  int row;
  if (row4 < CCLS) { in = wt; out = wn; row = row4; }
  else             { in = x;  out = xn; row = row4 - CCLS; }
  const float4* src = (const float4*)(in + (size_t)row * DIM);
  float4 v0 = src[lane];
  float4 v1 = src[lane + 64];
  float ss = v0.x*v0.x + v0.y*v0.y + v0.z*v0.z + v0.w*v0.w
           + v1.x*v1.x + v1.y*v1.y + v1.z*v1.z + v1.w*v1.w;
  #pragma unroll
  for (int off = 32; off > 0; off >>= 1) ss += __shfl_xor(ss, off, 64);
  float r = 1.0f / fmaxf(sqrtf(ss), 1e-12f);
  ushort4 o0, o1;
  o0.x = f2bf(v0.x * r); o0.y = f2bf(v0.y * r); o0.z = f2bf(v0.z * r); o0.w = f2bf(v0.w * r);
  o1.x = f2bf(v1.x * r); o1.y = f2bf(v1.y * r); o1.z = f2bf(v1.z * r); o1.w = f2bf(v1.w * r);
  ushort4* dst = (ushort4*)(out + (size_t)row * DIM);
  dst[lane]      = o0;
  dst[lane + 64] = o1;
}

// 256x128 tile GEMM (K=512, BK=64), 512 threads = 8 waves (4 m-rows x 2 n-cols),
// 64x64 per-wave tile, fused CosFace epilogue. partial[m][nt] transposed.
__global__ __launch_bounds__(512, 4) void cosface_gemm(
    const unsigned short* __restrict__ xn,
    const unsigned short* __restrict__ wn,
    const int* __restrict__ gt,
    float* __restrict__ partial,
    float* __restrict__ tgt) {
  __shared__ unsigned short lds_a[BM * 64];   // 32 KB
  __shared__ unsigned short lds_b[BN * 64];   // 16 KB
  __shared__ float lds_rowsum[BM];
  __shared__ int lds_gt[BM];

  const int tid = threadIdx.x;
  const int lane = tid & 63;
  const int w = tid >> 6;          // wave 0..7
  const int wm = w >> 1;           // 0..3  (64-row slice)
  const int wn_ = w & 1;           // 0..1  (64-col slice)
  const int mt = blockIdx.x;       // 0..1
  const int nt = blockIdx.y;       // 0..781

  if (tid < BM) {
    lds_rowsum[tid] = 0.f;
    lds_gt[tid] = gt[mt * BM + tid];
  }

  // Staging: chunk c -> row m = c>>3, slot qs = c&7, global chunk qg = qs^(m&7).
  // A: 2048 chunks (4/thread), B: 1024 chunks (2/thread).
  const unsigned short* ga[4];
  const unsigned short* gb[2];
  #pragma unroll
  for (int j = 0; j < 4; ++j) {
    int c = j * 512 + tid;
    int m = c >> 3;
    int qg = (c & 7) ^ (m & 7);
    ga[j] = xn + (size_t)(mt * BM + m) * DIM + qg * 8;
  }
  #pragma unroll
  for (int j = 0; j < 2; ++j) {
    int c = j * 512 + tid;
    int m = c >> 3;
    int qg = (c & 7) ^ (m & 7);
    int rowB = nt * BN + m;
    if (rowB >= CCLS) rowB = CCLS - 1;   // clamp; excluded in epilogue
    gb[j] = wn + (size_t)rowB * DIM + qg * 8;
  }

  f32x4 acc[4][4];
  #pragma unroll
  for (int i = 0; i < 4; ++i)
    #pragma unroll
    for (int j = 0; j < 4; ++j)
      acc[i][j] = (f32x4){0.f, 0.f, 0.f, 0.f};

  const int quad = lane >> 4;
  const int l15 = lane & 15;
  const int arow = wm * 64 + l15;   // A fragment row base
  const int brow = wn_ * 64 + l15;  // B fragment row base
  const int sw = (l15 & 7);         // swizzle component (i*16 doesn't change m&7)

  for (int kk = 0; kk < 8; ++kk) {
    #pragma unroll
    for (int j = 0; j < 4; ++j)
      async_copy16(ga[j] + kk * 64, &lds_a[(j * 512 + w * 64) * 8]);
    #pragma unroll
    for (int j = 0; j < 2; ++j)
      async_copy16(gb[j] + kk * 64, &lds_b[(j * 512 + w * 64) * 8]);
    __syncthreads();
    #pragma unroll
    for (int s = 0; s < 2; ++s) {
      bf16x8 af[4], bf[4];
      int q = s * 4 + quad;
      int qs = (q ^ sw) * 8;
      #pragma unroll
      for (int i = 0; i < 4; ++i) {
        af[i] = *(const bf16x8*)&lds_a[(arow + i * 16) * 64 + qs];
        bf[i] = *(const bf16x8*)&lds_b[(brow + i * 16) * 64 + qs];
      }
      #pragma unroll
      for (int i = 0; i < 4; ++i)
        #pragma unroll
        for (int j = 0; j < 4; ++j)
          acc[i][j] = __builtin_amdgcn_mfma_f32_16x16x32_bf16(af[i], bf[j], acc[i][j], 0, 0, 0);
    }
    __syncthreads();
  }

  // Epilogue: logit = 64*cos (-22.4 at gt); rowsum += sum_n exp(logit-64)
  #pragma unroll
  for (int i = 0; i < 4; ++i) {
    #pragma unroll
    for (int reg = 0; reg < 4; ++reg) {
      int m_loc = wm * 64 + i * 16 + quad * 4 + reg;
      int m_g = mt * BM + m_loc;
      int gtm = lds_gt[m_loc];
      float s = 0.f;
      #pragma unroll
      for (int j = 0; j < 4; ++j) {
        int n_g = nt * BN + wn_ * 64 + j * 16 + l15;
        float logit = 64.f * acc[i][j][reg];
        if (n_g == gtm) {
          logit -= 64.f * 0.35f;
          tgt[m_g] = logit;
        }
        if (n_g < CCLS) s += __expf(logit - 64.f);
      }
      #pragma unroll
      for (int off = 1; off < 16; off <<= 1) s += __shfl_xor(s, off, 64);
      if (l15 == 0) atomicAdd(&lds_rowsum[m_loc], s);
    }
  }
  __syncthreads();
  if (tid < BM)
    partial[(size_t)(mt * BM + tid) * NT + nt] = lds_rowsum[tid];
}

// One wave per row m: sum partial[m][0..NT) (contiguous), emit nll[m].
__global__ __launch_bounds__(64) void nll_rows(const float* __restrict__ partial,
                                               const float* __restrict__ tgt,
                                               float* __restrict__ nll) {
  int m = blockIdx.x;
  int lane = threadIdx.x;
  const float* row = partial + (size_t)m * NT;
  float s = 0.f;
  for (int t = lane; t < NT; t += 64) s += row[t];
  #pragma unroll
  for (int off = 32; off > 0; off >>= 1) s += __shfl_xor(s, off, 64);
  if (lane == 0) nll[m] = (logf(s) + 64.f) - tgt[m];
}

__global__ __launch_bounds__(512) void reduce_mean(const float* __restrict__ nll,
                                                   float* __restrict__ out) {
  __shared__ float red[BATCH];
  int m = threadIdx.x;
  red[m] = nll[m];
  __syncthreads();
  for (int k = 256; k > 0; k >>= 1) {
    if (m < k) red[m] += red[m + k];
    __syncthreads();
  }
  if (m == 0) out[0] = red[0] * (1.0f / BATCH);
}

extern "C" void kernel_launch(void* const* d_in, const int* in_sizes, int n_in,
                              void* d_out, int out_size, void* d_ws, size_t ws_size,
                              hipStream_t stream) {
  const float* x  = (const float*)d_in[0];
  const int*   gt = (const int*)d_in[1];
  const float* wt = (const float*)d_in[2];
  float* out = (float*)d_out;

  char* ws = (char*)d_ws;
  unsigned short* wn = (unsigned short*)ws;                                   // 102,400,000 B
  unsigned short* xn = (unsigned short*)(ws + 102400000);                     //     524,288 B
  float* partial     = (float*)(ws + 102400000 + 524288);                     //   1,601,536 B
  float* tgt         = (float*)(ws + 102400000 + 524288 + 1601536);           //       2,048 B
  float* nll         = (float*)(ws + 102400000 + 524288 + 1601536 + 2048);    //       2,048 B

  rownorm_all<<<(CCLS + BATCH) / 4, 256, 0, stream>>>(wt, x, wn, xn);
  cosface_gemm<<<dim3(2, NT), 512, 0, stream>>>(xn, wn, gt, partial, tgt);
  nll_rows<<<BATCH, 64, 0, stream>>>(partial, tgt, nll);
  reduce_mean<<<1, BATCH, 0, stream>>>(nll, out);
}

// Round 4
// 348.668 us; speedup vs baseline: 1.0537x; 1.0537x over previous
//
#include <hip/hip_runtime.h>
#include <hip/hip_bf16.h>

#define DIM 512
#define BATCH 512
#define CCLS 100000
#define BM 256
#define BN 128
#define NT 782   // ceil(100000/128)

typedef __attribute__((ext_vector_type(4))) float f32x4;

__device__ __forceinline__ void async_copy16(const unsigned char* g, unsigned char* l) {
  __builtin_amdgcn_global_load_lds((const __attribute__((address_space(1))) void*)g,
                                   (__attribute__((address_space(3))) void*)l, 16, 0, 0);
}

// One wave per row: read fp32 row, L2-normalize (fp32), write fp8 e4m3 row.
// Lane handles 8 CONTIGUOUS elements [8*lane, 8*lane+8) so the 8B fp8 store
// lands at byte offset 8*lane (coalesced int2 store).
__global__ __launch_bounds__(256) void rownorm_fp8(const float* __restrict__ wt,
                                                   const float* __restrict__ x,
                                                   unsigned char* __restrict__ wn,
                                                   unsigned char* __restrict__ xn) {
  int wave = threadIdx.x >> 6;
  int lane = threadIdx.x & 63;
  int row4 = blockIdx.x * 4 + wave;
  const float* in;
  unsigned char* out;
  int row;
  if (row4 < CCLS) { in = wt; out = wn; row = row4; }
  else             { in = x;  out = xn; row = row4 - CCLS; }
  const float4* src = (const float4*)(in + (size_t)row * DIM);
  float4 v0 = src[2 * lane];
  float4 v1 = src[2 * lane + 1];
  float ss = v0.x*v0.x + v0.y*v0.y + v0.z*v0.z + v0.w*v0.w
           + v1.x*v1.x + v1.y*v1.y + v1.z*v1.z + v1.w*v1.w;
  #pragma unroll
  for (int off = 32; off > 0; off >>= 1) ss += __shfl_xor(ss, off, 64);
  float r = 1.0f / fmaxf(sqrtf(ss), 1e-12f);
  int p0 = __builtin_amdgcn_cvt_pk_fp8_f32(v0.x * r, v0.y * r, 0, false);
  p0     = __builtin_amdgcn_cvt_pk_fp8_f32(v0.z * r, v0.w * r, p0, true);
  int p1 = __builtin_amdgcn_cvt_pk_fp8_f32(v1.x * r, v1.y * r, 0, false);
  p1     = __builtin_amdgcn_cvt_pk_fp8_f32(v1.z * r, v1.w * r, p1, true);
  ((int2*)(out + (size_t)row * DIM))[lane] = make_int2(p0, p1);
}

// 256x128 tile fp8 GEMM, K=512, BK=128 (4 barrier-iters), 512 threads = 8 waves
// (4 m x 2 n), 64x64 per-wave tile, mfma_f32_16x16x32_fp8_fp8, fused CosFace
// epilogue. LDS rows are 128 fp8 bytes (one BK slice), 16B-chunk XOR(m&7)
// swizzle -> 8B frag reads hit 8 banks x 2 lanes (2-way = free).
__global__ __launch_bounds__(512, 4) void cosface_gemm(
    const unsigned char* __restrict__ xn,
    const unsigned char* __restrict__ wn,
    const int* __restrict__ gt,
    float* __restrict__ partial,
    float* __restrict__ tgt) {
  __shared__ __align__(16) unsigned char lds_a[BM * 128];   // 32 KB
  __shared__ __align__(16) unsigned char lds_b[BN * 128];   // 16 KB
  __shared__ float lds_rowsum[BM];
  __shared__ int lds_gt[BM];

  const int tid = threadIdx.x;
  const int lane = tid & 63;
  const int w = tid >> 6;          // wave 0..7
  const int wm = w >> 1;           // 0..3  (64-row slice)
  const int wn_ = w & 1;           // 0..1  (64-col slice)
  const int mt = blockIdx.x;       // 0..1
  const int nt = blockIdx.y;       // 0..781

  if (tid < BM) {
    lds_rowsum[tid] = 0.f;
    lds_gt[tid] = gt[mt * BM + tid];
  }

  // Staging: 16B chunk c -> row m = c>>3, slot qs = c&7, global chunk
  // qg = qs ^ (m&7). A: 2048 chunks (4/thread), B: 1024 chunks (2/thread).
  const unsigned char* ga[4];
  const unsigned char* gb[2];
  #pragma unroll
  for (int j = 0; j < 4; ++j) {
    int c = j * 512 + tid;
    int m = c >> 3;
    int qg = (c & 7) ^ (m & 7);
    ga[j] = xn + (size_t)(mt * BM + m) * DIM + qg * 16;
  }
  #pragma unroll
  for (int j = 0; j < 2; ++j) {
    int c = j * 512 + tid;
    int m = c >> 3;
    int qg = (c & 7) ^ (m & 7);
    int rowB = nt * BN + m;
    if (rowB >= CCLS) rowB = CCLS - 1;   // clamp; excluded in epilogue
    gb[j] = wn + (size_t)rowB * DIM + qg * 16;
  }

  f32x4 acc[4][4];
  #pragma unroll
  for (int i = 0; i < 4; ++i)
    #pragma unroll
    for (int j = 0; j < 4; ++j)
      acc[i][j] = (f32x4){0.f, 0.f, 0.f, 0.f};

  const int quad = lane >> 4;
  const int l15 = lane & 15;
  const int arow = wm * 64 + l15;
  const int brow = wn_ * 64 + l15;
  const int swA = arow & 7;        // i*16 doesn't change m&7
  const int swB = brow & 7;

  for (int kk = 0; kk < 4; ++kk) {
    #pragma unroll
    for (int j = 0; j < 4; ++j)
      async_copy16(ga[j] + kk * 128, &lds_a[(j * 512 + w * 64) * 16]);
    #pragma unroll
    for (int j = 0; j < 2; ++j)
      async_copy16(gb[j] + kk * 128, &lds_b[(j * 512 + w * 64) * 16]);
    __syncthreads();
    #pragma unroll
    for (int s = 0; s < 4; ++s) {
      // granule g (8B) = s*4+quad within the 128B row; chunk cs = g>>1.
      int g = s * 4 + quad;
      int cs = g >> 1;
      int h = (g & 1) * 8;
      long long af[4], bf[4];
      #pragma unroll
      for (int i = 0; i < 4; ++i) {
        af[i] = *(const long long*)&lds_a[(arow + i * 16) * 128 + ((cs ^ swA) * 16) + h];
        bf[i] = *(const long long*)&lds_b[(brow + i * 16) * 128 + ((cs ^ swB) * 16) + h];
      }
      #pragma unroll
      for (int i = 0; i < 4; ++i)
        #pragma unroll
        for (int j = 0; j < 4; ++j)
          acc[i][j] = __builtin_amdgcn_mfma_f32_16x16x32_fp8_fp8(af[i], bf[j], acc[i][j], 0, 0, 0);
    }
    __syncthreads();
  }

  // Epilogue: logit = 64*cos (-22.4 at gt); rowsum += sum_n exp(logit-64)
  #pragma unroll
  for (int i = 0; i < 4; ++i) {
    #pragma unroll
    for (int reg = 0; reg < 4; ++reg) {
      int m_loc = wm * 64 + i * 16 + quad * 4 + reg;
      int m_g = mt * BM + m_loc;
      int gtm = lds_gt[m_loc];
      float s = 0.f;
      #pragma unroll
      for (int j = 0; j < 4; ++j) {
        int n_g = nt * BN + wn_ * 64 + j * 16 + l15;
        float logit = 64.f * acc[i][j][reg];
        if (n_g == gtm) {
          logit -= 64.f * 0.35f;
          tgt[m_g] = logit;
        }
        if (n_g < CCLS) s += __expf(logit - 64.f);
      }
      #pragma unroll
      for (int off = 1; off < 16; off <<= 1) s += __shfl_xor(s, off, 64);
      if (l15 == 0) atomicAdd(&lds_rowsum[m_loc], s);
    }
  }
  __syncthreads();
  if (tid < BM)
    partial[(size_t)(mt * BM + tid) * NT + nt] = lds_rowsum[tid];
}

// One wave per row m: sum partial[m][0..NT) (contiguous), emit nll[m].
__global__ __launch_bounds__(64) void nll_rows(const float* __restrict__ partial,
                                               const float* __restrict__ tgt,
                                               float* __restrict__ nll) {
  int m = blockIdx.x;
  int lane = threadIdx.x;
  const float* row = partial + (size_t)m * NT;
  float s = 0.f;
  for (int t = lane; t < NT; t += 64) s += row[t];
  #pragma unroll
  for (int off = 32; off > 0; off >>= 1) s += __shfl_xor(s, off, 64);
  if (lane == 0) nll[m] = (logf(s) + 64.f) - tgt[m];
}

__global__ __launch_bounds__(512) void reduce_mean(const float* __restrict__ nll,
                                                   float* __restrict__ out) {
  __shared__ float red[BATCH];
  int m = threadIdx.x;
  red[m] = nll[m];
  __syncthreads();
  for (int k = 256; k > 0; k >>= 1) {
    if (m < k) red[m] += red[m + k];
    __syncthreads();
  }
  if (m == 0) out[0] = red[0] * (1.0f / BATCH);
}

extern "C" void kernel_launch(void* const* d_in, const int* in_sizes, int n_in,
                              void* d_out, int out_size, void* d_ws, size_t ws_size,
                              hipStream_t stream) {
  const float* x  = (const float*)d_in[0];
  const int*   gt = (const int*)d_in[1];
  const float* wt = (const float*)d_in[2];
  float* out = (float*)d_out;

  char* ws = (char*)d_ws;
  unsigned char* wn = (unsigned char*)ws;                      //  51,200,000 B
  unsigned char* xn = (unsigned char*)(ws + 51200000);         //     262,144 B
  float* partial    = (float*)(ws + 51462144);                 //   1,601,536 B
  float* tgt        = (float*)(ws + 53063680);                 //       2,048 B
  float* nll        = (float*)(ws + 53065728);                 //       2,048 B

  rownorm_fp8<<<(CCLS + BATCH) / 4, 256, 0, stream>>>(wt, x, wn, xn);
  cosface_gemm<<<dim3(2, NT), 512, 0, stream>>>(xn, wn, gt, partial, tgt);
  nll_rows<<<BATCH, 64, 0, stream>>>(partial, tgt, nll);
  reduce_mean<<<1, BATCH, 0, stream>>>(nll, out);
}